// Round 1
// 346.733 us; speedup vs baseline: 1.0053x; 1.0053x over previous
//
#include <hip/hip_runtime.h>

#define NB 8
#define NC 21
#define HW (512 * 512)
#define BLOCKS_PER_SAMPLE 256                    // 1024 pixels per block
#define PIX_PER_BLOCK (HW / BLOCKS_PER_SAMPLE)   // 1024
#define THREADS 256                              // 1 float4 (4 pixels) per thread

// Kernel 1: per-pixel argmax over channels for pred & target, accumulate
// per-block confusion matrix in LDS, flush to global conf with atomics.
//
// R(this): batch ALL 21 channel loads into a register array before the
// argmax compare chain. The previous rolling-max loop carried bp/bt through
// every iteration, so the compiler register-minimized to VGPR=32 and kept
// only ~2 float4 loads in flight (one waitcnt per channel iteration ->
// latency-serialized, VALUBusy 6%, 3.0 TB/s delivered vs 6.3 achievable).
// Register arrays with full unroll (compile-time indices -- no scratch)
// force 21 loads in flight per wave; ~110 VGPR fits the 128 cap from
// __launch_bounds__(256,4) so occupancy (16 waves/CU) is preserved.
__global__ __launch_bounds__(THREADS, 4) void conf_kernel(
    const float* __restrict__ pred,
    const float* __restrict__ targ,
    int* __restrict__ conf /* [NB][NC][NC] */) {
  __shared__ int lconf[NC * NC];
  const int tid = threadIdx.x;
  for (int i = tid; i < NC * NC; i += THREADS) lconf[i] = 0;
  __syncthreads();

  const int b   = blockIdx.x / BLOCKS_PER_SAMPLE;
  const int blk = blockIdx.x % BLOCKS_PER_SAMPLE;
  const float* __restrict__ pbase = pred + (size_t)b * NC * HW;
  const float* __restrict__ tbase = targ + (size_t)b * NC * HW;
  const int p0 = blk * PIX_PER_BLOCK + tid * 4;  // 16B-aligned

  // ---- phase 1: prediction argmax, fully batched loads ----
  float4 p[NC];
#pragma unroll
  for (int c = 0; c < NC; ++c) {
    p[c] = *(const float4*)(pbase + (size_t)c * HW + p0);
  }
  int ip0 = 0, ip1 = 0, ip2 = 0, ip3 = 0;
  float bx = p[0].x, by = p[0].y, bz = p[0].z, bw = p[0].w;
#pragma unroll
  for (int c = 1; c < NC; ++c) {
    if (p[c].x > bx) { bx = p[c].x; ip0 = c; }
    if (p[c].y > by) { by = p[c].y; ip1 = c; }
    if (p[c].z > bz) { bz = p[c].z; ip2 = c; }
    if (p[c].w > bw) { bw = p[c].w; ip3 = c; }
  }

  // ---- phase 2: target argmax, fully batched loads ----
  float4 t[NC];
#pragma unroll
  for (int c = 0; c < NC; ++c) {
    t[c] = *(const float4*)(tbase + (size_t)c * HW + p0);
  }
  int it0 = 0, it1 = 0, it2 = 0, it3 = 0;
  float cx = t[0].x, cy = t[0].y, cz = t[0].z, cw = t[0].w;
#pragma unroll
  for (int c = 1; c < NC; ++c) {
    if (t[c].x > cx) { cx = t[c].x; it0 = c; }
    if (t[c].y > cy) { cy = t[c].y; it1 = c; }
    if (t[c].z > cz) { cz = t[c].z; it2 = c; }
    if (t[c].w > cw) { cw = t[c].w; it3 = c; }
  }

  atomicAdd(&lconf[it0 * NC + ip0], 1);
  atomicAdd(&lconf[it1 * NC + ip1], 1);
  atomicAdd(&lconf[it2 * NC + ip2], 1);
  atomicAdd(&lconf[it3 * NC + ip3], 1);
  __syncthreads();

  int* __restrict__ gconf = conf + b * NC * NC;
  for (int i = tid; i < NC * NC; i += THREADS) {
    int v = lconf[i];
    if (v) atomicAdd(&gconf[i], v);
  }
}

// Kernel 2: conf -> per-class IoU -> per-sample mean over valid classes ->
// batch mean scalar.
__global__ __launch_bounds__(256) void iou_kernel(const int* __restrict__ conf,
                                                  float* __restrict__ out) {
  __shared__ float iou_sum[NB];
  __shared__ int valid_cnt[NB];
  const int tid = threadIdx.x;
  if (tid < NB) { iou_sum[tid] = 0.f; valid_cnt[tid] = 0; }
  __syncthreads();

  if (tid < NB * NC) {
    const int b = tid / NC, c = tid % NC;
    const int* __restrict__ m = conf + b * NC * NC;
    const int tp = m[c * NC + c];
    int row = 0, col = 0;
#pragma unroll
    for (int j = 0; j < NC; ++j) {
      row += m[c * NC + j];  // TP + FN
      col += m[j * NC + c];  // TP + FP
    }
    if (tp > 0) {
      const float denom = (float)(row + col - tp);  // TP + FN + FP
      atomicAdd(&iou_sum[b], (float)tp / denom);
      atomicAdd(&valid_cnt[b], 1);
    }
  }
  __syncthreads();

  if (tid == 0) {
    float s = 0.f;
    for (int b = 0; b < NB; ++b) {
      const int n = valid_cnt[b] > 0 ? valid_cnt[b] : 1;
      s += iou_sum[b] / (float)n;
    }
    out[0] = s / (float)NB;
  }
}

extern "C" void kernel_launch(void* const* d_in, const int* in_sizes, int n_in,
                              void* d_out, int out_size, void* d_ws, size_t ws_size,
                              hipStream_t stream) {
  const float* pred = (const float*)d_in[0];
  const float* targ = (const float*)d_in[1];
  float* out = (float*)d_out;
  int* conf = (int*)d_ws;  // NB*NC*NC ints = 14112 B

  hipMemsetAsync(conf, 0, NB * NC * NC * sizeof(int), stream);
  conf_kernel<<<NB * BLOCKS_PER_SAMPLE, THREADS, 0, stream>>>(pred, targ, conf);
  iou_kernel<<<1, 256, 0, stream>>>(conf, out);
}

// Round 2
// 345.190 us; speedup vs baseline: 1.0098x; 1.0045x over previous
//
#include <hip/hip_runtime.h>

#define NB 8
#define NC 21
#define HW (512 * 512)
#define BLOCKS_PER_SAMPLE 256                    // 1024 pixels per block
#define PIX_PER_BLOCK (HW / BLOCKS_PER_SAMPLE)   // 1024
#define THREADS 256                              // 1 float4 (4 pixels) per thread

// Kernel 1: per-pixel argmax over channels for pred & target, accumulate
// per-block confusion matrix in LDS, flush to global conf with atomics.
//
// R2: FORCE the 21-load batch with __builtin_amdgcn_sched_barrier(0).
// R1's register-array + #pragma unroll was re-sunk by the machine scheduler
// (VGPR stayed 40, dur unchanged at 119 us, VALUBusy 6%) -- LLVM's
// pressure-minimizing heuristic interleaves load+compare, leaving ~2 loads
// in flight per wave (latency-serialized at 3.0 TB/s delivered vs 6.3
// achievable). sched_barrier(0) is a hard fence: all 21 loads must issue
// before any compare, so regalloc must keep ~84 data VGPRs live (fits the
// 128 cap from __launch_bounds__(256,4)) and waits become staggered
// vmcnt(N) as compares consume p[0..20] in load order.
__global__ __launch_bounds__(THREADS, 4) void conf_kernel(
    const float* __restrict__ pred,
    const float* __restrict__ targ,
    int* __restrict__ conf /* [NB][NC][NC] */) {
  __shared__ int lconf[NC * NC];
  const int tid = threadIdx.x;
  for (int i = tid; i < NC * NC; i += THREADS) lconf[i] = 0;
  __syncthreads();

  const int b   = blockIdx.x / BLOCKS_PER_SAMPLE;
  const int blk = blockIdx.x % BLOCKS_PER_SAMPLE;
  const float* __restrict__ pbase = pred + (size_t)b * NC * HW;
  const float* __restrict__ tbase = targ + (size_t)b * NC * HW;
  const int p0 = blk * PIX_PER_BLOCK + tid * 4;  // 16B-aligned

  // ---- phase 1: prediction -- issue ALL 21 loads, then compare ----
  float4 p[NC];
#pragma unroll
  for (int c = 0; c < NC; ++c) {
    p[c] = *(const float4*)(pbase + (size_t)c * HW + p0);
  }
  __builtin_amdgcn_sched_barrier(0);  // nothing crosses: 21 loads in flight
  int ip0 = 0, ip1 = 0, ip2 = 0, ip3 = 0;
  float bx = p[0].x, by = p[0].y, bz = p[0].z, bw = p[0].w;
#pragma unroll
  for (int c = 1; c < NC; ++c) {
    if (p[c].x > bx) { bx = p[c].x; ip0 = c; }
    if (p[c].y > by) { by = p[c].y; ip1 = c; }
    if (p[c].z > bz) { bz = p[c].z; ip2 = c; }
    if (p[c].w > bw) { bw = p[c].w; ip3 = c; }
  }
  __builtin_amdgcn_sched_barrier(0);  // keep target loads below compares
                                      // (84+84 live regs would spill)

  // ---- phase 2: target -- issue ALL 21 loads, then compare ----
  float4 t[NC];
#pragma unroll
  for (int c = 0; c < NC; ++c) {
    t[c] = *(const float4*)(tbase + (size_t)c * HW + p0);
  }
  __builtin_amdgcn_sched_barrier(0);  // 21 loads in flight
  int it0 = 0, it1 = 0, it2 = 0, it3 = 0;
  float cx = t[0].x, cy = t[0].y, cz = t[0].z, cw = t[0].w;
#pragma unroll
  for (int c = 1; c < NC; ++c) {
    if (t[c].x > cx) { cx = t[c].x; it0 = c; }
    if (t[c].y > cy) { cy = t[c].y; it1 = c; }
    if (t[c].z > cz) { cz = t[c].z; it2 = c; }
    if (t[c].w > cw) { cw = t[c].w; it3 = c; }
  }

  atomicAdd(&lconf[it0 * NC + ip0], 1);
  atomicAdd(&lconf[it1 * NC + ip1], 1);
  atomicAdd(&lconf[it2 * NC + ip2], 1);
  atomicAdd(&lconf[it3 * NC + ip3], 1);
  __syncthreads();

  int* __restrict__ gconf = conf + b * NC * NC;
  for (int i = tid; i < NC * NC; i += THREADS) {
    int v = lconf[i];
    if (v) atomicAdd(&gconf[i], v);
  }
}

// Kernel 2: conf -> per-class IoU -> per-sample mean over valid classes ->
// batch mean scalar.
__global__ __launch_bounds__(256) void iou_kernel(const int* __restrict__ conf,
                                                  float* __restrict__ out) {
  __shared__ float iou_sum[NB];
  __shared__ int valid_cnt[NB];
  const int tid = threadIdx.x;
  if (tid < NB) { iou_sum[tid] = 0.f; valid_cnt[tid] = 0; }
  __syncthreads();

  if (tid < NB * NC) {
    const int b = tid / NC, c = tid % NC;
    const int* __restrict__ m = conf + b * NC * NC;
    const int tp = m[c * NC + c];
    int row = 0, col = 0;
#pragma unroll
    for (int j = 0; j < NC; ++j) {
      row += m[c * NC + j];  // TP + FN
      col += m[j * NC + c];  // TP + FP
    }
    if (tp > 0) {
      const float denom = (float)(row + col - tp);  // TP + FN + FP
      atomicAdd(&iou_sum[b], (float)tp / denom);
      atomicAdd(&valid_cnt[b], 1);
    }
  }
  __syncthreads();

  if (tid == 0) {
    float s = 0.f;
    for (int b = 0; b < NB; ++b) {
      const int n = valid_cnt[b] > 0 ? valid_cnt[b] : 1;
      s += iou_sum[b] / (float)n;
    }
    out[0] = s / (float)NB;
  }
}

extern "C" void kernel_launch(void* const* d_in, const int* in_sizes, int n_in,
                              void* d_out, int out_size, void* d_ws, size_t ws_size,
                              hipStream_t stream) {
  const float* pred = (const float*)d_in[0];
  const float* targ = (const float*)d_in[1];
  float* out = (float*)d_out;
  int* conf = (int*)d_ws;  // NB*NC*NC ints = 14112 B

  hipMemsetAsync(conf, 0, NB * NC * NC * sizeof(int), stream);
  conf_kernel<<<NB * BLOCKS_PER_SAMPLE, THREADS, 0, stream>>>(pred, targ, conf);
  iou_kernel<<<1, 256, 0, stream>>>(conf, out);
}

// Round 3
// 342.957 us; speedup vs baseline: 1.0163x; 1.0065x over previous
//
#include <hip/hip_runtime.h>

#define NB 8
#define NC 21
#define HW (512 * 512)
#define BLOCKS_PER_SAMPLE 256                    // 1024 pixels per block
#define PIX_PER_BLOCK (HW / BLOCKS_PER_SAMPLE)   // 1024
#define THREADS 256                              // 1 float4 (4 pixels) per thread

typedef float f32x4 __attribute__((ext_vector_type(4)));
typedef unsigned int u32;

// Kernel 1: per-pixel argmax over channels for pred & target, accumulate
// per-block confusion matrix in LDS, flush to global conf with atomics.
//
// R3: inline-asm forced MLP. R1 (register array) and R2 (sched_barrier)
// both failed to change codegen (VGPR 40/48, dur pinned 119 us): plain
// loads have no chain dependence on sched_barrier at ISel, so SelectionDAG
// re-interleaves load+compare before scheduling regions exist. asm volatile
// global_load_dwordx4 is strictly ordered among itself -> 21 loads issue
// back-to-back. SGPR-base + 32-bit voffset form keeps addressing at ~1 VGPR
// (84 data VGPRs total, fits 128 cap at 4 waves/EU). The drain asm ties all
// 21 float4s as "+v" in-outs so compares data-depend on the s_waitcnt and
// cannot be hoisted above it (rule #18), + sched_barrier(0) fence.
__global__ __launch_bounds__(THREADS, 4) void conf_kernel(
    const float* __restrict__ pred,
    const float* __restrict__ targ,
    int* __restrict__ conf /* [NB][NC][NC] */) {
  __shared__ int lconf[NC * NC];
  const int tid = threadIdx.x;
  for (int i = tid; i < NC * NC; i += THREADS) lconf[i] = 0;
  __syncthreads();

  const int b   = blockIdx.x / BLOCKS_PER_SAMPLE;
  const int blk = blockIdx.x % BLOCKS_PER_SAMPLE;
  const float* __restrict__ pbase = pred + (size_t)b * NC * HW;
  const float* __restrict__ tbase = targ + (size_t)b * NC * HW;
  const int p0 = blk * PIX_PER_BLOCK + tid * 4;  // 16B-aligned
  const u32 voff = (u32)p0 * 4u;                 // byte voffset, uniform base/chan

#define LOAD4(dst, base)                                            \
  asm volatile("global_load_dwordx4 %0, %1, %2"                     \
               : "=v"(dst) : "v"(voff), "s"(base))

#define DRAIN21(P)                                                           \
  asm volatile("s_waitcnt vmcnt(0)"                                          \
               : "+v"(P[0]), "+v"(P[1]), "+v"(P[2]), "+v"(P[3]), "+v"(P[4]), \
                 "+v"(P[5]), "+v"(P[6]), "+v"(P[7]), "+v"(P[8]), "+v"(P[9]), \
                 "+v"(P[10]), "+v"(P[11]), "+v"(P[12]), "+v"(P[13]),         \
                 "+v"(P[14]), "+v"(P[15]), "+v"(P[16]), "+v"(P[17]),         \
                 "+v"(P[18]), "+v"(P[19]), "+v"(P[20])                       \
               :                                                             \
               : "memory")

  // ---- phase 1: prediction -- 21 loads in flight, one drain, compare ----
  f32x4 p[NC];
#pragma unroll
  for (int c = 0; c < NC; ++c) {
    LOAD4(p[c], pbase + (size_t)c * HW);  // base is wave-uniform -> SGPR pair
  }
  DRAIN21(p);
  __builtin_amdgcn_sched_barrier(0);

  int ip0 = 0, ip1 = 0, ip2 = 0, ip3 = 0;
  float bx = p[0][0], by = p[0][1], bz = p[0][2], bw = p[0][3];
#pragma unroll
  for (int c = 1; c < NC; ++c) {
    if (p[c][0] > bx) { bx = p[c][0]; ip0 = c; }
    if (p[c][1] > by) { by = p[c][1]; ip1 = c; }
    if (p[c][2] > bz) { bz = p[c][2]; ip2 = c; }
    if (p[c][3] > bw) { bw = p[c][3]; ip3 = c; }
  }
  // keep targ batch from overlapping pred live range (84+84 > 128 cap)
  __builtin_amdgcn_sched_barrier(0);

  // ---- phase 2: target -- same structure ----
  f32x4 t[NC];
#pragma unroll
  for (int c = 0; c < NC; ++c) {
    LOAD4(t[c], tbase + (size_t)c * HW);
  }
  DRAIN21(t);
  __builtin_amdgcn_sched_barrier(0);

  int it0 = 0, it1 = 0, it2 = 0, it3 = 0;
  float cx = t[0][0], cy = t[0][1], cz = t[0][2], cw = t[0][3];
#pragma unroll
  for (int c = 1; c < NC; ++c) {
    if (t[c][0] > cx) { cx = t[c][0]; it0 = c; }
    if (t[c][1] > cy) { cy = t[c][1]; it1 = c; }
    if (t[c][2] > cz) { cz = t[c][2]; it2 = c; }
    if (t[c][3] > cw) { cw = t[c][3]; it3 = c; }
  }

#undef LOAD4
#undef DRAIN21

  atomicAdd(&lconf[it0 * NC + ip0], 1);
  atomicAdd(&lconf[it1 * NC + ip1], 1);
  atomicAdd(&lconf[it2 * NC + ip2], 1);
  atomicAdd(&lconf[it3 * NC + ip3], 1);
  __syncthreads();

  int* __restrict__ gconf = conf + b * NC * NC;
  for (int i = tid; i < NC * NC; i += THREADS) {
    int v = lconf[i];
    if (v) atomicAdd(&gconf[i], v);
  }
}

// Kernel 2: conf -> per-class IoU -> per-sample mean over valid classes ->
// batch mean scalar.
__global__ __launch_bounds__(256) void iou_kernel(const int* __restrict__ conf,
                                                  float* __restrict__ out) {
  __shared__ float iou_sum[NB];
  __shared__ int valid_cnt[NB];
  const int tid = threadIdx.x;
  if (tid < NB) { iou_sum[tid] = 0.f; valid_cnt[tid] = 0; }
  __syncthreads();

  if (tid < NB * NC) {
    const int b = tid / NC, c = tid % NC;
    const int* __restrict__ m = conf + b * NC * NC;
    const int tp = m[c * NC + c];
    int row = 0, col = 0;
#pragma unroll
    for (int j = 0; j < NC; ++j) {
      row += m[c * NC + j];  // TP + FN
      col += m[j * NC + c];  // TP + FP
    }
    if (tp > 0) {
      const float denom = (float)(row + col - tp);  // TP + FN + FP
      atomicAdd(&iou_sum[b], (float)tp / denom);
      atomicAdd(&valid_cnt[b], 1);
    }
  }
  __syncthreads();

  if (tid == 0) {
    float s = 0.f;
    for (int b = 0; b < NB; ++b) {
      const int n = valid_cnt[b] > 0 ? valid_cnt[b] : 1;
      s += iou_sum[b] / (float)n;
    }
    out[0] = s / (float)NB;
  }
}

extern "C" void kernel_launch(void* const* d_in, const int* in_sizes, int n_in,
                              void* d_out, int out_size, void* d_ws, size_t ws_size,
                              hipStream_t stream) {
  const float* pred = (const float*)d_in[0];
  const float* targ = (const float*)d_in[1];
  float* out = (float*)d_out;
  int* conf = (int*)d_ws;  // NB*NC*NC ints = 14112 B

  hipMemsetAsync(conf, 0, NB * NC * NC * sizeof(int), stream);
  conf_kernel<<<NB * BLOCKS_PER_SAMPLE, THREADS, 0, stream>>>(pred, targ, conf);
  iou_kernel<<<1, 256, 0, stream>>>(conf, out);
}